// Round 3
// baseline (2458.258 us; speedup 1.0000x reference)
//
#include <hip/hip_runtime.h>

// Fused CARAFE++ (B=4, C=256, H=W=64, SCALE=2, K=5, G=1, MID=64, ENC_OUT=100).
// ALL inputs/outputs are FP32 (reference setup_inputs uses jnp.float32; rounds
// 1-2 mis-cast them as bf16 -> low-half mantissa bits became bf16 exponents ->
// Inf/NaN through softmax). ONE kernel, zero d_ws usage.
// grid = 256 blocks (b*64 + tile), 512 threads.
// LDS: xs 18432 + fw 26624 + wst 14400 = 59456 B.

__global__ __launch_bounds__(512) void carafe_fused(
    const float* __restrict__ x,    // (4,256,64,64)
    const float* __restrict__ Wc,   // (64,256)
    const float* __restrict__ bc,   // (64,)
    const float* __restrict__ We,   // (100,64,3,3)
    const float* __restrict__ be,   // (100,)
    float* __restrict__ out) {      // (4,256,128,128) flat as [b][c][i][j][p]

    __shared__ float xs[32 * 144];  // one 32-ch chunk of the 12x12 x tile
    __shared__ float fw[6656];      // fs[m*100+pos] then wks[px*104+o] (disjoint)
    __shared__ float wst[3600];     // 4 m-slices of W_enc: [mm*900 + o*9 + rs]

    const int t = threadIdx.x;
    const int blk = blockIdx.x;
    const int b = blk >> 6, tile = blk & 63;
    const int i0 = (tile >> 3) << 3, j0 = (tile & 7) << 3;
    const int wid = t >> 6, pix = t & 63;   // wid: wave id (uniform per wave)
    const int li = pix >> 3, lj = pix & 7;

    // ---------------- P1: feat = relu(W_comp . x + b_comp) on 10x10 halo ----
    float facc[13];
#pragma unroll
    for (int q = 0; q < 13; q++) facc[q] = 0.f;

    for (int cc = 0; cc < 8; cc++) {        // 8 chunks x 32 channels
        for (int idx = t; idx < 32 * 144; idx += 512) {
            int c = idx / 144, pos = idx - c * 144;
            int r = pos / 12, u = pos - r * 12;
            int gi = i0 + r - 2, gj = j0 + u - 2;
            float v = 0.f;
            if ((unsigned)gi < 64u && (unsigned)gj < 64u)
                v = x[(((b * 256 + cc * 32 + c) << 12) + (gi << 6) + gj)];
            xs[idx] = v;
        }
        __syncthreads();
#pragma unroll
        for (int q = 0; q < 13; q++) {
            int idx = q * 512 + t;
            if (idx < 6400) {               // idx = m*100 + pos (pos on 10x10)
                int m = idx / 100, pos = idx - m * 100;
                int fi = pos / 10, fj = pos - fi * 10;
                int tp = (fi + 1) * 12 + fj + 1;
                const float* wr = Wc + m * 256 + cc * 32;
                float a = facc[q];
                for (int c = 0; c < 32; c++)
                    a += xs[c * 144 + tp] * wr[c];
                facc[q] = a;
            }
        }
        __syncthreads();
    }
    // bias + relu -> fs; SAME-pad of the enc conv zero-pads FEAT, so halo
    // positions outside the image must be 0 (not relu(b_comp)).
#pragma unroll
    for (int q = 0; q < 13; q++) {
        int idx = q * 512 + t;
        if (idx < 6400) {
            int m = idx / 100, pos = idx - m * 100;
            int fi = pos / 10, fj = pos - fi * 10;
            int gi = i0 + fi - 1, gj = j0 + fj - 1;
            float v = facc[q] + bc[m];
            v = v > 0.f ? v : 0.f;
            if ((unsigned)gi >= 64u || (unsigned)gj >= 64u) v = 0.f;
            fw[idx] = v;
        }
    }

    // ---------------- P2: enc 3x3 conv -> logits (regs) ----------------
    float acc[13];
#pragma unroll
    for (int q = 0; q < 13; q++) acc[q] = 0.f;

    for (int mb = 0; mb < 16; mb++) {
        for (int idx = t; idx < 3600; idx += 512) {   // stage 4 m-slices of W_enc
            int mm = idx / 900, rem = idx - mm * 900;
            int o = rem / 9, rs = rem - o * 9;
            wst[idx] = We[o * 576 + (mb * 4 + mm) * 9 + rs];
        }
        __syncthreads();                  // also makes fw (fs) writes visible
#pragma unroll
        for (int mm = 0; mm < 4; mm++) {
            const float* fb = fw + (mb * 4 + mm) * 100 + li * 10 + lj;
            float f9[9];
#pragma unroll
            for (int r = 0; r < 3; r++)
#pragma unroll
                for (int s = 0; s < 3; s++) f9[r * 3 + s] = fb[r * 10 + s];
#pragma unroll
            for (int q = 0; q < 13; q++) {
                int o = q * 8 + wid;      // wave-uniform -> LDS broadcast
                if (o < 100) {
                    const float* wr = wst + mm * 900 + o * 9;
                    float a = acc[q];
#pragma unroll
                    for (int rs = 0; rs < 9; rs++) a += f9[rs] * wr[rs];
                    acc[q] = a;
                }
            }
        }
        __syncthreads();
    }

    // logits -> fw[px*104 + o]; fs region is dead now
#pragma unroll
    for (int q = 0; q < 13; q++) {
        int o = q * 8 + wid;
        if (o < 100) fw[pix * 104 + o] = acc[q];
    }
    __syncthreads();

    // ---------------- P2b: softmax over 25 taps; restore as wks[px][k*4+p] ---
    // enc channel o maps to (p, k) = (o / 25, o % 25); softmax over k per p.
    float sv[25];
    float inv = 0.f;
    const int sp = t >> 6, spx = t & 63;
    const bool act = (t < 256);
    if (act) {
        float mx = -1e30f;
#pragma unroll
        for (int k = 0; k < 25; k++) {
            sv[k] = fw[spx * 104 + sp * 25 + k] + be[sp * 25 + k];
            mx = fmaxf(mx, sv[k]);
        }
        float s = 0.f;
#pragma unroll
        for (int k = 0; k < 25; k++) { sv[k] = __expf(sv[k] - mx); s += sv[k]; }
        inv = 1.f / s;
    }
    __syncthreads();
    if (act) {
#pragma unroll
        for (int k = 0; k < 25; k++) fw[spx * 104 + k * 4 + sp] = sv[k] * inv;
    }
    __syncthreads();

    // ---------------- P3: gather + pixel rearrange ----------------
    float w[25][4];
    const float4* wp = (const float4*)(fw + pix * 104);
#pragma unroll
    for (int k = 0; k < 25; k++) {
        float4 ww = wp[k];
        w[k][0] = ww.x; w[k][1] = ww.y; w[k][2] = ww.z; w[k][3] = ww.w;
    }
    const int pgl = ((i0 + li) << 6) + (j0 + lj);
    for (int cc = 0; cc < 8; cc++) {
        for (int idx = t; idx < 32 * 144; idx += 512) {   // re-stage chunk cc
            int c = idx / 144, pos = idx - c * 144;
            int r = pos / 12, u = pos - r * 12;
            int gi = i0 + r - 2, gj = j0 + u - 2;
            float v = 0.f;
            if ((unsigned)gi < 64u && (unsigned)gj < 64u)
                v = x[(((b * 256 + cc * 32 + c) << 12) + (gi << 6) + gj)];
            xs[idx] = v;
        }
        __syncthreads();
        for (int c8 = wid; c8 < 32; c8 += 8) {
            const float* xc = xs + c8 * 144 + li * 12 + lj;
            float a0 = 0.f, a1 = 0.f, a2 = 0.f, a3 = 0.f;
#pragma unroll
            for (int dy = 0; dy < 5; dy++) {
#pragma unroll
                for (int dx = 0; dx < 5; dx++) {
                    float xv = xc[dy * 12 + dx];
                    const int k = dy * 5 + dx;
                    a0 += xv * w[k][0];
                    a1 += xv * w[k][1];
                    a2 += xv * w[k][2];
                    a3 += xv * w[k][3];
                }
            }
            int c = cc * 32 + c8;
            float4 o4 = make_float4(a0, a1, a2, a3);
            *(float4*)(out + (((long long)(b * 256 + c)) << 14) + pgl * 4) = o4;
        }
        __syncthreads();
    }
}

extern "C" void kernel_launch(void* const* d_in, const int* in_sizes, int n_in,
                              void* d_out, int out_size, void* d_ws, size_t ws_size,
                              hipStream_t stream) {
    const float* x  = (const float*)d_in[0];
    const float* Wc = (const float*)d_in[1];
    const float* bc = (const float*)d_in[2];
    const float* We = (const float*)d_in[3];
    const float* be = (const float*)d_in[4];
    float* out = (float*)d_out;

    carafe_fused<<<256, 512, 0, stream>>>(x, Wc, bc, We, be, out);
}

// Round 4
// 390.049 us; speedup vs baseline: 6.3024x; 6.3024x over previous
//
#include <hip/hip_runtime.h>

// CARAFE++ (B=4, C=256, H=W=64, SCALE=2, K=5, G=1, MID=64, ENC_OUT=100). FP32 I/O.
// Round-3 fused kernel passed but spilled ~100 regs/thread -> 6.1 GB scratch
// traffic, VALUBusy 3.7%. Round 4: 4 register-light kernels via d_ws (11.9 MB),
// with the proven fused kernel as fallback if ws_size is insufficient.
//
// ws layout (float offsets):
#define OFF_FEAT 0              // feat [b][m][4096]              1,048,576 f
#define OFF_WET  1048576        // W_enc^T [m*9+rs][p][28pad]        64,512 f
#define OFF_WCT  1113088        // W_comp^T [c][m]                   16,384 f
#define OFF_WK   1129472        // softmax wk [b*4096][p][28pad]  1,835,008 f
#define WS_FLOATS 2964480       // = 11,857,920 bytes

// ---------------- prep: weight transposes ----------------
__global__ __launch_bounds__(256) void prep_kernel(
    const float* __restrict__ Wc, const float* __restrict__ We,
    float* __restrict__ ws) {
    int i = blockIdx.x * 256 + threadIdx.x;
    if (i < 16384) {                       // WcT[c*64+m] = Wc[m][c]
        int c = i >> 6, m = i & 63;
        ws[OFF_WCT + i] = Wc[m * 256 + c];
    }
    if (i < 64512) {                       // Wet[(m*9+rs)*112 + p*28 + kk]
        int mrs = i / 112, rem = i - mrs * 112;
        int p = rem / 28, kk = rem - p * 28;
        ws[OFF_WET + i] = (kk < 25) ? We[(p * 25 + kk) * 576 + mrs] : 0.f;
    }
}

// ---------------- K1: 1x1 compress conv + relu ----------------
// 64 pixels/block, 256 thr = 64 lanes x 4 m-chunks(16). acc[16] only.
__global__ __launch_bounds__(256) void compress_kernel(
    const float* __restrict__ x, const float* __restrict__ bc,
    const float* __restrict__ ws, float* __restrict__ feat) {
    __shared__ float xs[128 * 64];         // 32 KB: half the channels
    int pixbase = blockIdx.x * 64;
    int b = pixbase >> 12, pl = pixbase & 4095;
    int lane = threadIdx.x & 63;
    int chunk = __builtin_amdgcn_readfirstlane(threadIdx.x >> 6);
    const float* wct = ws + OFF_WCT;
    float acc[16];
#pragma unroll
    for (int q = 0; q < 16; q++) acc[q] = 0.f;
    for (int h = 0; h < 2; h++) {
        int ch0 = h << 7;
        for (int idx = threadIdx.x; idx < 128 * 64; idx += 256) {
            int c = idx >> 6, pp = idx & 63;
            xs[idx] = x[((b * 256 + ch0 + c) << 12) + pl + pp];
        }
        __syncthreads();
        for (int c = 0; c < 128; c++) {
            float xv = xs[(c << 6) + lane];
            const float* wr = wct + (ch0 + c) * 64 + chunk * 16;  // SGPR addr
#pragma unroll
            for (int q = 0; q < 16; q++) acc[q] += xv * wr[q];
        }
        __syncthreads();
    }
#pragma unroll
    for (int q = 0; q < 16; q++) {
        int m = chunk * 16 + q;
        float v = acc[q] + bc[m];
        feat[(b * 64 + m) * 4096 + pl + lane] = v > 0.f ? v : 0.f;
    }
}

// ---------------- K2: 3x3 enc conv + bias + softmax(25) ----------------
// 8x8 tile/block, 512 thr = 64 px x (4 p x 2 k-halves). acc[13] only.
// k-half hi computes a 13th tap against the ZERO pad -> harmless no-op.
__global__ __launch_bounds__(512) void enc_kernel(
    const float* __restrict__ be, const float* __restrict__ ws,
    float* __restrict__ wkout) {
    __shared__ float fs[6400];             // feat halo [m][10x10] / later logits [px][100]
    __shared__ float wt[8064];             // 8 m-slices of Wet (contig copy)
    int t = threadIdx.x;
    int blk = blockIdx.x;
    int b = blk >> 6, tile = blk & 63;
    int i0 = (tile >> 3) << 3, j0 = (tile & 7) << 3;
    int pix = t & 63;
    int li = pix >> 3, lj = pix & 7;
    int g = __builtin_amdgcn_readfirstlane(t >> 6);  // 0..7, wave-uniform
    int p = g >> 1, k0 = (g & 1) * 13;
    const float* feat = ws + OFF_FEAT;
    const float* wet = ws + OFF_WET;

    for (int idx = t; idx < 6400; idx += 512) {      // stage feat halo (0-padded)
        int m = idx / 100, pos = idx - m * 100;
        int r = pos / 10, s = pos - r * 10;
        int gi = i0 + r - 1, gj = j0 + s - 1;
        float v = 0.f;
        if ((unsigned)gi < 64u && (unsigned)gj < 64u)
            v = feat[(b * 64 + m) * 4096 + (gi << 6) + gj];
        fs[idx] = v;
    }

    float acc[13];
#pragma unroll
    for (int q = 0; q < 13; q++) acc[q] = 0.f;

    for (int mb = 0; mb < 8; mb++) {
        for (int idx = t; idx < 8064; idx += 512)    // contiguous, coalesced
            wt[idx] = wet[mb * 8064 + idx];
        __syncthreads();                             // also covers fs writes (mb=0)
#pragma unroll
        for (int mm = 0; mm < 8; mm++) {
            const float* fb = fs + ((mb << 3) + mm) * 100 + li * 10 + lj;
            const float* wrow = wt + mm * 9 * 112 + p * 28 + k0;  // SGPR addr
#pragma unroll
            for (int rs = 0; rs < 9; rs++) {
                float f = fb[(rs / 3) * 10 + (rs % 3)];
                const float* wr = wrow + rs * 112;   // 13 uniform LDS broadcasts
#pragma unroll
                for (int q = 0; q < 13; q++) acc[q] += f * wr[q];
            }
        }
        __syncthreads();
    }

    // logits (+bias) -> fs[pix*100 + p*25 + k]; fs halo is dead past the barrier
#pragma unroll
    for (int q = 0; q < 13; q++) {
        int k = k0 + q;
        if (k < 25) fs[pix * 100 + p * 25 + k] = acc[q] + be[p * 25 + k];
    }
    __syncthreads();

    if (t < 256) {                                   // softmax: thread = (pix, p)
        int sp = t >> 6, spx = t & 63;
        const float* lg = fs + spx * 100 + sp * 25;
        float sv[25], mx = -1e30f;
#pragma unroll
        for (int k = 0; k < 25; k++) { sv[k] = lg[k]; mx = fmaxf(mx, sv[k]); }
        float s = 0.f;
#pragma unroll
        for (int k = 0; k < 25; k++) { sv[k] = __expf(sv[k] - mx); s += sv[k]; }
        float inv = 1.f / s;
        int pgl = ((i0 + (spx >> 3)) << 6) + j0 + (spx & 7);
        float* wp = wkout + ((b << 12) + pgl) * 112 + sp * 28;
#pragma unroll
        for (int k = 0; k < 25; k++) wp[k] = sv[k] * inv;
    }
}

// ---------------- K3: gather + pixel rearrange ----------------
// block = (b, row i); 256 thr = 64 j x 2 p-pairs x 2 c-halves. w[2][25]=50 regs.
__global__ __launch_bounds__(256) void gather_kernel(
    const float* __restrict__ x, const float* __restrict__ ws,
    float* __restrict__ out) {
    __shared__ float xs[32 * 340];                   // 32 ch x 5 rows x 68 (43.5 KB)
    int t = threadIdx.x;
    int blk = blockIdx.x;
    int b = blk >> 6, i = blk & 63;
    int j = t & 63;
    int g = t >> 6;                                  // 0..3
    int ph = g >> 1, ch = g & 1;
    float w0[25], w1[25];
    {
        const float* wp = ws + OFF_WK + ((b << 12) + (i << 6) + j) * 112 + ph * 56;
#pragma unroll
        for (int k = 0; k < 25; k++) { w0[k] = wp[k]; w1[k] = wp[28 + k]; }
    }
    for (int cc = 0; cc < 8; cc++) {
        for (int idx = t; idx < 10880; idx += 256) { // stage 32-ch row slab
            int c = idx / 340, rem = idx - c * 340;
            int dy = rem / 68, u = rem - dy * 68;
            int gi = i - 2 + dy, gj = u - 2;
            float v = 0.f;
            if ((unsigned)gi < 64u && (unsigned)gj < 64u)
                v = x[((b * 256 + (cc << 5) + c) << 12) + (gi << 6) + gj];
            xs[idx] = v;
        }
        __syncthreads();
        for (int c2 = ch; c2 < 32; c2 += 2) {
            const float* xb = xs + c2 * 340 + j;
            float a0 = 0.f, a1 = 0.f;
#pragma unroll
            for (int dy = 0; dy < 5; dy++) {
#pragma unroll
                for (int dx = 0; dx < 5; dx++) {
                    float xv = xb[dy * 68 + dx];
                    int k = dy * 5 + dx;
                    a0 += xv * w0[k];
                    a1 += xv * w1[k];
                }
            }
            int c = (cc << 5) + c2;
            float2 o2 = make_float2(a0, a1);
            *(float2*)(out + (((b * 256 + c) << 12) + (i << 6) + j) * 4 + ph * 2) = o2;
        }
        __syncthreads();
    }
}

// ---------------- fallback: round-3 fused kernel (correct, slow) ----------------
__global__ __launch_bounds__(512) void carafe_fused(
    const float* __restrict__ x, const float* __restrict__ Wc,
    const float* __restrict__ bc, const float* __restrict__ We,
    const float* __restrict__ be, float* __restrict__ out) {
    __shared__ float xs[32 * 144];
    __shared__ float fw[6656];
    __shared__ float wst[3600];
    const int t = threadIdx.x;
    const int blk = blockIdx.x;
    const int b = blk >> 6, tile = blk & 63;
    const int i0 = (tile >> 3) << 3, j0 = (tile & 7) << 3;
    const int wid = t >> 6, pix = t & 63;
    const int li = pix >> 3, lj = pix & 7;
    float facc[13];
#pragma unroll
    for (int q = 0; q < 13; q++) facc[q] = 0.f;
    for (int cc = 0; cc < 8; cc++) {
        for (int idx = t; idx < 32 * 144; idx += 512) {
            int c = idx / 144, pos = idx - c * 144;
            int r = pos / 12, u = pos - r * 12;
            int gi = i0 + r - 2, gj = j0 + u - 2;
            float v = 0.f;
            if ((unsigned)gi < 64u && (unsigned)gj < 64u)
                v = x[(((b * 256 + cc * 32 + c) << 12) + (gi << 6) + gj)];
            xs[idx] = v;
        }
        __syncthreads();
#pragma unroll
        for (int q = 0; q < 13; q++) {
            int idx = q * 512 + t;
            if (idx < 6400) {
                int m = idx / 100, pos = idx - m * 100;
                int fi = pos / 10, fj = pos - fi * 10;
                int tp = (fi + 1) * 12 + fj + 1;
                const float* wr = Wc + m * 256 + cc * 32;
                float a = facc[q];
                for (int c = 0; c < 32; c++) a += xs[c * 144 + tp] * wr[c];
                facc[q] = a;
            }
        }
        __syncthreads();
    }
#pragma unroll
    for (int q = 0; q < 13; q++) {
        int idx = q * 512 + t;
        if (idx < 6400) {
            int m = idx / 100, pos = idx - m * 100;
            int fi = pos / 10, fj = pos - fi * 10;
            int gi = i0 + fi - 1, gj = j0 + fj - 1;
            float v = facc[q] + bc[m];
            v = v > 0.f ? v : 0.f;
            if ((unsigned)gi >= 64u || (unsigned)gj >= 64u) v = 0.f;
            fw[idx] = v;
        }
    }
    float acc[13];
#pragma unroll
    for (int q = 0; q < 13; q++) acc[q] = 0.f;
    for (int mb = 0; mb < 16; mb++) {
        for (int idx = t; idx < 3600; idx += 512) {
            int mm = idx / 900, rem = idx - mm * 900;
            int o = rem / 9, rs = rem - o * 9;
            wst[idx] = We[o * 576 + (mb * 4 + mm) * 9 + rs];
        }
        __syncthreads();
#pragma unroll
        for (int mm = 0; mm < 4; mm++) {
            const float* fb = fw + (mb * 4 + mm) * 100 + li * 10 + lj;
            float f9[9];
#pragma unroll
            for (int r = 0; r < 3; r++)
#pragma unroll
                for (int s = 0; s < 3; s++) f9[r * 3 + s] = fb[r * 10 + s];
#pragma unroll
            for (int q = 0; q < 13; q++) {
                int o = q * 8 + wid;
                if (o < 100) {
                    const float* wr = wst + mm * 900 + o * 9;
                    float a = acc[q];
#pragma unroll
                    for (int rs = 0; rs < 9; rs++) a += f9[rs] * wr[rs];
                    acc[q] = a;
                }
            }
        }
        __syncthreads();
    }
#pragma unroll
    for (int q = 0; q < 13; q++) {
        int o = q * 8 + wid;
        if (o < 100) fw[pix * 104 + o] = acc[q];
    }
    __syncthreads();
    float sv[25];
    float inv = 0.f;
    const int sp = t >> 6, spx = t & 63;
    const bool act = (t < 256);
    if (act) {
        float mx = -1e30f;
#pragma unroll
        for (int k = 0; k < 25; k++) {
            sv[k] = fw[spx * 104 + sp * 25 + k] + be[sp * 25 + k];
            mx = fmaxf(mx, sv[k]);
        }
        float s = 0.f;
#pragma unroll
        for (int k = 0; k < 25; k++) { sv[k] = __expf(sv[k] - mx); s += sv[k]; }
        inv = 1.f / s;
    }
    __syncthreads();
    if (act) {
#pragma unroll
        for (int k = 0; k < 25; k++) fw[spx * 104 + k * 4 + sp] = sv[k] * inv;
    }
    __syncthreads();
    float w[25][4];
    const float4* wp = (const float4*)(fw + pix * 104);
#pragma unroll
    for (int k = 0; k < 25; k++) {
        float4 ww = wp[k];
        w[k][0] = ww.x; w[k][1] = ww.y; w[k][2] = ww.z; w[k][3] = ww.w;
    }
    const int pgl = ((i0 + li) << 6) + (j0 + lj);
    for (int cc = 0; cc < 8; cc++) {
        for (int idx = t; idx < 32 * 144; idx += 512) {
            int c = idx / 144, pos = idx - c * 144;
            int r = pos / 12, u = pos - r * 12;
            int gi = i0 + r - 2, gj = j0 + u - 2;
            float v = 0.f;
            if ((unsigned)gi < 64u && (unsigned)gj < 64u)
                v = x[(((b * 256 + cc * 32 + c) << 12) + (gi << 6) + gj)];
            xs[idx] = v;
        }
        __syncthreads();
        for (int c8 = wid; c8 < 32; c8 += 8) {
            const float* xc = xs + c8 * 144 + li * 12 + lj;
            float a0 = 0.f, a1 = 0.f, a2 = 0.f, a3 = 0.f;
#pragma unroll
            for (int dy = 0; dy < 5; dy++) {
#pragma unroll
                for (int dx = 0; dx < 5; dx++) {
                    float xv = xc[dy * 12 + dx];
                    const int k = dy * 5 + dx;
                    a0 += xv * w[k][0];
                    a1 += xv * w[k][1];
                    a2 += xv * w[k][2];
                    a3 += xv * w[k][3];
                }
            }
            int c = cc * 32 + c8;
            float4 o4 = make_float4(a0, a1, a2, a3);
            *(float4*)(out + (((long long)(b * 256 + c)) << 14) + pgl * 4) = o4;
        }
        __syncthreads();
    }
}

extern "C" void kernel_launch(void* const* d_in, const int* in_sizes, int n_in,
                              void* d_out, int out_size, void* d_ws, size_t ws_size,
                              hipStream_t stream) {
    const float* x  = (const float*)d_in[0];
    const float* Wc = (const float*)d_in[1];
    const float* bc = (const float*)d_in[2];
    const float* We = (const float*)d_in[3];
    const float* be = (const float*)d_in[4];
    float* out = (float*)d_out;

    if (ws_size >= (size_t)WS_FLOATS * sizeof(float)) {
        float* ws = (float*)d_ws;
        prep_kernel<<<252, 256, 0, stream>>>(Wc, We, ws);
        compress_kernel<<<256, 256, 0, stream>>>(x, bc, ws, ws + OFF_FEAT);
        enc_kernel<<<256, 512, 0, stream>>>(be, ws, ws + OFF_WK);
        gather_kernel<<<256, 256, 0, stream>>>(x, ws, out);
    } else {
        carafe_fused<<<256, 512, 0, stream>>>(x, Wc, bc, We, be, out);
    }
}

// Round 5
// 227.966 us; speedup vs baseline: 10.7834x; 1.7110x over previous
//
#include <hip/hip_runtime.h>

// CARAFE++ (B=4, C=256, H=W=64, SCALE=2, K=5, G=1, MID=64, ENC_OUT=100). FP32 I/O.
// R4: 390us, gather 152us @ 10.6% occupancy (grid 256 = 1 block/CU, serial
// stage/barrier phases). R5: grid 8x on gather, 4x on compress; enc loses its
// 258KB/block LDS weight round-trip (scalar loads); wk relaid [o][pix] so
// gather's 50 weight loads are coalesced; div-free staging loops.
//
// ws layout (float offsets):
#define OFF_FEAT 0              // feat [b][m][4096]               1,048,576 f
#define OFF_WET  1048576        // W_enc^T [m*9+rs][p*28+k pad]       64,512 f
#define OFF_WCT  1113088        // W_comp^T [c][m]                    16,384 f
#define OFF_WK   1129472        // wk2 [p*25+k][b*4096+pix]        1,638,400 f
#define WS_FLOATS 2767872       // = 11,071,488 bytes

// ---------------- prep: weight transposes ----------------
__global__ __launch_bounds__(256) void prep_kernel(
    const float* __restrict__ Wc, const float* __restrict__ We,
    float* __restrict__ ws) {
    int i = blockIdx.x * 256 + threadIdx.x;
    if (i < 16384) {                       // WcT[c*64+m] = Wc[m][c]
        int c = i >> 6, m = i & 63;
        ws[OFF_WCT + i] = Wc[m * 256 + c];
    }
    if (i < 64512) {                       // Wet[(m*9+rs)*112 + p*28 + kk]
        int mrs = i / 112, rem = i - mrs * 112;
        int p = rem / 28, kk = rem - p * 28;
        ws[OFF_WET + i] = (kk < 25) ? We[(p * 25 + kk) * 576 + mrs] : 0.f;
    }
}

// ---------------- K1: 1x1 compress conv + relu ----------------
// grid 1024 = 256 px-groups x 4 m-quarters. 256 thr = 64 lanes x 4 chunks(4 m).
__global__ __launch_bounds__(256) void compress_kernel(
    const float* __restrict__ x, const float* __restrict__ bc,
    const float* __restrict__ ws, float* __restrict__ feat) {
    __shared__ float xs[128 * 64];         // 32 KB: half the channels
    int blk = blockIdx.x;
    int pxg = blk >> 2, mq = blk & 3;
    int pixbase = pxg * 64;
    int b = pixbase >> 12, pl = pixbase & 4095;
    int lane = threadIdx.x & 63;
    int chunk = __builtin_amdgcn_readfirstlane(threadIdx.x >> 6);
    int m0 = mq * 16 + chunk * 4;          // wave-uniform
    const float* wct = ws + OFF_WCT;
    float acc[4];
#pragma unroll
    for (int q = 0; q < 4; q++) acc[q] = 0.f;
    for (int h = 0; h < 2; h++) {
        int ch0 = h << 7;
        for (int idx = threadIdx.x; idx < 128 * 64; idx += 256) {
            int c = idx >> 6, pp = idx & 63;
            xs[idx] = x[((b * 256 + ch0 + c) << 12) + pl + pp];
        }
        __syncthreads();
        for (int c = 0; c < 128; c++) {
            float xv = xs[(c << 6) + lane];
            const float* wr = wct + (ch0 + c) * 64 + m0;   // uniform -> s_load
#pragma unroll
            for (int q = 0; q < 4; q++) acc[q] += xv * wr[q];
        }
        __syncthreads();
    }
#pragma unroll
    for (int q = 0; q < 4; q++) {
        int m = m0 + q;
        float v = acc[q] + bc[m];
        feat[(b * 64 + m) * 4096 + pl + lane] = v > 0.f ? v : 0.f;
    }
}

// ---------------- K2: 3x3 enc conv + bias + softmax(25) ----------------
// grid 256 (b x 8x8 tile), 512 thr = 64 px x (4 p x 2 k-halves).
// Weights via wave-uniform scalar loads (no LDS staging, 2 barriers total).
__global__ __launch_bounds__(512) void enc_kernel(
    const float* __restrict__ be, const float* __restrict__ ws,
    float* __restrict__ wkout) {
    __shared__ float fs[6400];             // feat halo [m][10x10] / later logits [px][100]
    int t = threadIdx.x;
    int blk = blockIdx.x;
    int b = blk >> 6, tile = blk & 63;
    int i0 = (tile >> 3) << 3, j0 = (tile & 7) << 3;
    int pix = t & 63;
    int li = pix >> 3, lj = pix & 7;
    int g = __builtin_amdgcn_readfirstlane(t >> 6);  // 0..7, wave-uniform
    int p = g >> 1, k0 = (g & 1) * 13;
    const float* feat = ws + OFF_FEAT;
    const float* wet = ws + OFF_WET + p * 28 + k0;   // uniform base

    for (int idx = t; idx < 6400; idx += 512) {      // stage feat halo (0-padded)
        int m = idx / 100, pos = idx - m * 100;
        int r = pos / 10, s = pos - r * 10;
        int gi = i0 + r - 1, gj = j0 + s - 1;
        float v = 0.f;
        if ((unsigned)gi < 64u && (unsigned)gj < 64u)
            v = feat[(b * 64 + m) * 4096 + (gi << 6) + gj];
        fs[idx] = v;
    }
    __syncthreads();

    float acc[13];
#pragma unroll
    for (int q = 0; q < 13; q++) acc[q] = 0.f;

    for (int m = 0; m < 64; m++) {
        const float* fb = fs + m * 100 + li * 10 + lj;
        float f9[9];
#pragma unroll
        for (int r = 0; r < 3; r++)
#pragma unroll
            for (int s = 0; s < 3; s++) f9[r * 3 + s] = fb[r * 10 + s];
        const float* wrow = wet + m * 9 * 112;       // uniform -> s_load_dwordx
#pragma unroll
        for (int rs = 0; rs < 9; rs++) {
            float f = f9[rs];
            const float* wr = wrow + rs * 112;
#pragma unroll
            for (int q = 0; q < 13; q++) acc[q] += f * wr[q];
        }
    }
    __syncthreads();                                 // halo reads done

    // logits (+bias) -> fs[pix*100 + p*25 + k] (k-half hi's q=12 is pad, skip)
#pragma unroll
    for (int q = 0; q < 13; q++) {
        int k = k0 + q;
        if (k < 25) fs[pix * 100 + p * 25 + k] = acc[q] + be[p * 25 + k];
    }
    __syncthreads();

    if (t < 256) {                                   // softmax: thread = (pix, p)
        int sp = t >> 6, spx = t & 63;
        const float* lg = fs + spx * 100 + sp * 25;
        float sv[25], mx = -1e30f;
#pragma unroll
        for (int k = 0; k < 25; k++) { sv[k] = lg[k]; mx = fmaxf(mx, sv[k]); }
        float s = 0.f;
#pragma unroll
        for (int k = 0; k < 25; k++) { sv[k] = __expf(sv[k] - mx); s += sv[k]; }
        float inv = 1.f / s;
        int pgl = ((i0 + (spx >> 3)) << 6) + j0 + (spx & 7);
        float* wp = wkout + (sp * 25) * 16384 + (b << 12) + pgl;
#pragma unroll
        for (int k = 0; k < 25; k++) wp[k * 16384] = sv[k] * inv;  // coalesced
    }
}

// ---------------- K3: gather + pixel rearrange ----------------
// grid 2048 = (b*64+i)*8 + cc(32 ch). 256 thr = 64 j x (2 p-pairs x 2 c-halves).
__global__ __launch_bounds__(256) void gather_kernel(
    const float* __restrict__ x, const float* __restrict__ ws,
    float* __restrict__ out) {
    __shared__ float xs[32 * 5 * 68];                // 43.5 KB
    int t = threadIdx.x;
    int blk = blockIdx.x;
    int cc = blk & 7;
    int bi = blk >> 3;
    int b = bi >> 6, i = bi & 63;
    int j = t & 63;
    int g = t >> 6;
    int ph = g >> 1, ch = g & 1;

    // coalesced wk loads: wk2[(p*25+k)*16384 + b*4096 + i*64 + j]
    float w0[25], w1[25];
    {
        const float* wp = ws + OFF_WK + (ph * 2 * 25) * 16384 + (b << 12) + (i << 6) + j;
#pragma unroll
        for (int k = 0; k < 25; k++) {
            w0[k] = wp[k * 16384];
            w1[k] = wp[(25 + k) * 16384];
        }
    }

    // div-free staging: only the aligned 64-float core is real; edges are zero.
    {
        int lane = t & 63, cd0 = t >> 6;             // (c,dy) pairs, 4 at a time
        for (int cd = cd0; cd < 160; cd += 4) {
            int c = cd / 5, dy = cd - c * 5;
            int gi = i - 2 + dy;
            float v = 0.f;
            if ((unsigned)gi < 64u)
                v = x[((b * 256 + (cc << 5) + c) << 12) + (gi << 6) + lane];
            float* row = xs + cd * 68;
            row[2 + lane] = v;
            if (lane < 2) row[lane] = 0.f;           // gj < 0 pad
            if (lane >= 62) row[lane + 4] = 0.f;     // gj >= 64 pad
        }
    }
    __syncthreads();

    for (int c2 = ch; c2 < 32; c2 += 2) {
        const float* xb = xs + (c2 * 5) * 68 + j;    // u = j+dx -> gj = j+dx-2
        float a0 = 0.f, a1 = 0.f;
#pragma unroll
        for (int dy = 0; dy < 5; dy++) {
#pragma unroll
            for (int dx = 0; dx < 5; dx++) {
                float xv = xb[dy * 68 + dx];
                int k = dy * 5 + dx;
                a0 += xv * w0[k];
                a1 += xv * w1[k];
            }
        }
        int c = (cc << 5) + c2;
        float2 o2 = make_float2(a0, a1);
        *(float2*)(out + (((b * 256 + c) << 12) + (i << 6) + j) * 4 + ph * 2) = o2;
    }
}

// ---------------- fallback: round-3 fused kernel (correct, slow) ----------------
__global__ __launch_bounds__(512) void carafe_fused(
    const float* __restrict__ x, const float* __restrict__ Wc,
    const float* __restrict__ bc, const float* __restrict__ We,
    const float* __restrict__ be, float* __restrict__ out) {
    __shared__ float xs[32 * 144];
    __shared__ float fw[6656];
    __shared__ float wst[3600];
    const int t = threadIdx.x;
    const int blk = blockIdx.x;
    const int b = blk >> 6, tile = blk & 63;
    const int i0 = (tile >> 3) << 3, j0 = (tile & 7) << 3;
    const int wid = t >> 6, pix = t & 63;
    const int li = pix >> 3, lj = pix & 7;
    float facc[13];
#pragma unroll
    for (int q = 0; q < 13; q++) facc[q] = 0.f;
    for (int cc = 0; cc < 8; cc++) {
        for (int idx = t; idx < 32 * 144; idx += 512) {
            int c = idx / 144, pos = idx - c * 144;
            int r = pos / 12, u = pos - r * 12;
            int gi = i0 + r - 2, gj = j0 + u - 2;
            float v = 0.f;
            if ((unsigned)gi < 64u && (unsigned)gj < 64u)
                v = x[(((b * 256 + cc * 32 + c) << 12) + (gi << 6) + gj)];
            xs[idx] = v;
        }
        __syncthreads();
#pragma unroll
        for (int q = 0; q < 13; q++) {
            int idx = q * 512 + t;
            if (idx < 6400) {
                int m = idx / 100, pos = idx - m * 100;
                int fi = pos / 10, fj = pos - fi * 10;
                int tp = (fi + 1) * 12 + fj + 1;
                const float* wr = Wc + m * 256 + cc * 32;
                float a = facc[q];
                for (int c = 0; c < 32; c++) a += xs[c * 144 + tp] * wr[c];
                facc[q] = a;
            }
        }
        __syncthreads();
    }
#pragma unroll
    for (int q = 0; q < 13; q++) {
        int idx = q * 512 + t;
        if (idx < 6400) {
            int m = idx / 100, pos = idx - m * 100;
            int fi = pos / 10, fj = pos - fi * 10;
            int gi = i0 + fi - 1, gj = j0 + fj - 1;
            float v = facc[q] + bc[m];
            v = v > 0.f ? v : 0.f;
            if ((unsigned)gi >= 64u || (unsigned)gj >= 64u) v = 0.f;
            fw[idx] = v;
        }
    }
    float acc[13];
#pragma unroll
    for (int q = 0; q < 13; q++) acc[q] = 0.f;
    for (int mb = 0; mb < 16; mb++) {
        for (int idx = t; idx < 3600; idx += 512) {
            int mm = idx / 900, rem = idx - mm * 900;
            int o = rem / 9, rs = rem - o * 9;
            wst[idx] = We[o * 576 + (mb * 4 + mm) * 9 + rs];
        }
        __syncthreads();
#pragma unroll
        for (int mm = 0; mm < 4; mm++) {
            const float* fb = fw + (mb * 4 + mm) * 100 + li * 10 + lj;
            float f9[9];
#pragma unroll
            for (int r = 0; r < 3; r++)
#pragma unroll
                for (int s = 0; s < 3; s++) f9[r * 3 + s] = fb[r * 10 + s];
#pragma unroll
            for (int q = 0; q < 13; q++) {
                int o = q * 8 + wid;
                if (o < 100) {
                    const float* wr = wst + mm * 900 + o * 9;
                    float a = acc[q];
#pragma unroll
                    for (int rs = 0; rs < 9; rs++) a += f9[rs] * wr[rs];
                    acc[q] = a;
                }
            }
        }
        __syncthreads();
    }
#pragma unroll
    for (int q = 0; q < 13; q++) {
        int o = q * 8 + wid;
        if (o < 100) fw[pix * 104 + o] = acc[q];
    }
    __syncthreads();
    float sv[25];
    float inv = 0.f;
    const int sp = t >> 6, spx = t & 63;
    const bool act = (t < 256);
    if (act) {
        float mx = -1e30f;
#pragma unroll
        for (int k = 0; k < 25; k++) {
            sv[k] = fw[spx * 104 + sp * 25 + k] + be[sp * 25 + k];
            mx = fmaxf(mx, sv[k]);
        }
        float s = 0.f;
#pragma unroll
        for (int k = 0; k < 25; k++) { sv[k] = __expf(sv[k] - mx); s += sv[k]; }
        inv = 1.f / s;
    }
    __syncthreads();
    if (act) {
#pragma unroll
        for (int k = 0; k < 25; k++) fw[spx * 104 + k * 4 + sp] = sv[k] * inv;
    }
    __syncthreads();
    float w[25][4];
    const float4* wp = (const float4*)(fw + pix * 104);
#pragma unroll
    for (int k = 0; k < 25; k++) {
        float4 ww = wp[k];
        w[k][0] = ww.x; w[k][1] = ww.y; w[k][2] = ww.z; w[k][3] = ww.w;
    }
    const int pgl = ((i0 + li) << 6) + (j0 + lj);
    for (int cc = 0; cc < 8; cc++) {
        for (int idx = t; idx < 32 * 144; idx += 512) {
            int c = idx / 144, pos = idx - c * 144;
            int r = pos / 12, u = pos - r * 12;
            int gi = i0 + r - 2, gj = j0 + u - 2;
            float v = 0.f;
            if ((unsigned)gi < 64u && (unsigned)gj < 64u)
                v = x[(((b * 256 + cc * 32 + c) << 12) + (gi << 6) + gj)];
            xs[idx] = v;
        }
        __syncthreads();
        for (int c8 = wid; c8 < 32; c8 += 8) {
            const float* xc = xs + c8 * 144 + li * 12 + lj;
            float a0 = 0.f, a1 = 0.f, a2 = 0.f, a3 = 0.f;
#pragma unroll
            for (int dy = 0; dy < 5; dy++) {
#pragma unroll
                for (int dx = 0; dx < 5; dx++) {
                    float xv = xc[dy * 12 + dx];
                    const int k = dy * 5 + dx;
                    a0 += xv * w[k][0];
                    a1 += xv * w[k][1];
                    a2 += xv * w[k][2];
                    a3 += xv * w[k][3];
                }
            }
            int c = cc * 32 + c8;
            float4 o4 = make_float4(a0, a1, a2, a3);
            *(float4*)(out + (((long long)(b * 256 + c)) << 14) + pgl * 4) = o4;
        }
        __syncthreads();
    }
}

extern "C" void kernel_launch(void* const* d_in, const int* in_sizes, int n_in,
                              void* d_out, int out_size, void* d_ws, size_t ws_size,
                              hipStream_t stream) {
    const float* x  = (const float*)d_in[0];
    const float* Wc = (const float*)d_in[1];
    const float* bc = (const float*)d_in[2];
    const float* We = (const float*)d_in[3];
    const float* be = (const float*)d_in[4];
    float* out = (float*)d_out;

    if (ws_size >= (size_t)WS_FLOATS * sizeof(float)) {
        float* ws = (float*)d_ws;
        prep_kernel<<<252, 256, 0, stream>>>(Wc, We, ws);
        compress_kernel<<<1024, 256, 0, stream>>>(x, bc, ws, ws + OFF_FEAT);
        enc_kernel<<<256, 512, 0, stream>>>(be, ws, ws + OFF_WK);
        gather_kernel<<<2048, 256, 0, stream>>>(x, ws, out);
    } else {
        carafe_fused<<<256, 512, 0, stream>>>(x, Wc, bc, We, be, out);
    }
}

// Round 6
// 198.836 us; speedup vs baseline: 12.3632x; 1.1465x over previous
//
#include <hip/hip_runtime.h>

// CARAFE++ (B=4, C=256, H=W=64, SCALE=2, K=5, G=1, MID=64, ENC_OUT=100). FP32 I/O.
// R5: 228us; gather 72us @ 26% occupancy (43.5KB LDS -> 3 blocks/CU).
// R6: gather 16-ch chunks (21.8KB LDS, grid 4096 -> 7 blocks/CU, 28 waves);
// compress 16KB staging phases. enc untouched (no counters yet).
//
// ws layout (float offsets):
#define OFF_FEAT 0              // feat [b][m][4096]               1,048,576 f
#define OFF_WET  1048576        // W_enc^T [m*9+rs][p*28+k pad]       64,512 f
#define OFF_WCT  1113088        // W_comp^T [c][m]                    16,384 f
#define OFF_WK   1129472        // wk2 [p*25+k][b*4096+pix]        1,638,400 f
#define WS_FLOATS 2767872       // = 11,071,488 bytes

// ---------------- prep: weight transposes ----------------
__global__ __launch_bounds__(256) void prep_kernel(
    const float* __restrict__ Wc, const float* __restrict__ We,
    float* __restrict__ ws) {
    int i = blockIdx.x * 256 + threadIdx.x;
    if (i < 16384) {                       // WcT[c*64+m] = Wc[m][c]
        int c = i >> 6, m = i & 63;
        ws[OFF_WCT + i] = Wc[m * 256 + c];
    }
    if (i < 64512) {                       // Wet[(m*9+rs)*112 + p*28 + kk]
        int mrs = i / 112, rem = i - mrs * 112;
        int p = rem / 28, kk = rem - p * 28;
        ws[OFF_WET + i] = (kk < 25) ? We[(p * 25 + kk) * 576 + mrs] : 0.f;
    }
}

// ---------------- K1: 1x1 compress conv + relu ----------------
// grid 1024 = 256 px-groups x 4 m-quarters. 256 thr = 64 lanes x 4 chunks(4 m).
// 4 staging phases of 64 ch (16 KB LDS) -> more blocks/CU than R5's 32 KB.
__global__ __launch_bounds__(256) void compress_kernel(
    const float* __restrict__ x, const float* __restrict__ bc,
    const float* __restrict__ ws, float* __restrict__ feat) {
    __shared__ float xs[64 * 64];          // 16 KB
    int blk = blockIdx.x;
    int pxg = blk >> 2, mq = blk & 3;
    int pixbase = pxg * 64;
    int b = pixbase >> 12, pl = pixbase & 4095;
    int lane = threadIdx.x & 63;
    int chunk = __builtin_amdgcn_readfirstlane(threadIdx.x >> 6);
    int m0 = mq * 16 + chunk * 4;          // wave-uniform
    const float* wct = ws + OFF_WCT;
    float acc[4];
#pragma unroll
    for (int q = 0; q < 4; q++) acc[q] = 0.f;
    for (int h = 0; h < 4; h++) {
        int ch0 = h << 6;
        for (int idx = threadIdx.x; idx < 64 * 64; idx += 256) {
            int c = idx >> 6, pp = idx & 63;
            xs[idx] = x[((b * 256 + ch0 + c) << 12) + pl + pp];
        }
        __syncthreads();
        for (int c = 0; c < 64; c++) {
            float xv = xs[(c << 6) + lane];
            const float* wr = wct + (ch0 + c) * 64 + m0;   // uniform -> s_load
#pragma unroll
            for (int q = 0; q < 4; q++) acc[q] += xv * wr[q];
        }
        __syncthreads();
    }
#pragma unroll
    for (int q = 0; q < 4; q++) {
        int m = m0 + q;
        float v = acc[q] + bc[m];
        feat[(b * 64 + m) * 4096 + pl + lane] = v > 0.f ? v : 0.f;
    }
}

// ---------------- K2: 3x3 enc conv + bias + softmax(25) ----------------
// grid 256 (b x 8x8 tile), 512 thr = 64 px x (4 p x 2 k-halves).
// Weights via wave-uniform scalar loads (no LDS staging, 2 barriers total).
__global__ __launch_bounds__(512) void enc_kernel(
    const float* __restrict__ be, const float* __restrict__ ws,
    float* __restrict__ wkout) {
    __shared__ float fs[6400];             // feat halo [m][10x10] / later logits [px][100]
    int t = threadIdx.x;
    int blk = blockIdx.x;
    int b = blk >> 6, tile = blk & 63;
    int i0 = (tile >> 3) << 3, j0 = (tile & 7) << 3;
    int pix = t & 63;
    int li = pix >> 3, lj = pix & 7;
    int g = __builtin_amdgcn_readfirstlane(t >> 6);  // 0..7, wave-uniform
    int p = g >> 1, k0 = (g & 1) * 13;
    const float* feat = ws + OFF_FEAT;
    const float* wet = ws + OFF_WET + p * 28 + k0;   // uniform base

    for (int idx = t; idx < 6400; idx += 512) {      // stage feat halo (0-padded)
        int m = idx / 100, pos = idx - m * 100;
        int r = pos / 10, s = pos - r * 10;
        int gi = i0 + r - 1, gj = j0 + s - 1;
        float v = 0.f;
        if ((unsigned)gi < 64u && (unsigned)gj < 64u)
            v = feat[(b * 64 + m) * 4096 + (gi << 6) + gj];
        fs[idx] = v;
    }
    __syncthreads();

    float acc[13];
#pragma unroll
    for (int q = 0; q < 13; q++) acc[q] = 0.f;

    for (int m = 0; m < 64; m++) {
        const float* fb = fs + m * 100 + li * 10 + lj;
        float f9[9];
#pragma unroll
        for (int r = 0; r < 3; r++)
#pragma unroll
            for (int s = 0; s < 3; s++) f9[r * 3 + s] = fb[r * 10 + s];
        const float* wrow = wet + m * 9 * 112;       // uniform -> s_load_dwordx
#pragma unroll
        for (int rs = 0; rs < 9; rs++) {
            float f = f9[rs];
            const float* wr = wrow + rs * 112;
#pragma unroll
            for (int q = 0; q < 13; q++) acc[q] += f * wr[q];
        }
    }
    __syncthreads();                                 // halo reads done

    // logits (+bias) -> fs[pix*100 + p*25 + k] (k-half hi's q=12 is pad, skip)
#pragma unroll
    for (int q = 0; q < 13; q++) {
        int k = k0 + q;
        if (k < 25) fs[pix * 100 + p * 25 + k] = acc[q] + be[p * 25 + k];
    }
    __syncthreads();

    if (t < 256) {                                   // softmax: thread = (pix, p)
        int sp = t >> 6, spx = t & 63;
        const float* lg = fs + spx * 100 + sp * 25;
        float sv[25], mx = -1e30f;
#pragma unroll
        for (int k = 0; k < 25; k++) { sv[k] = lg[k]; mx = fmaxf(mx, sv[k]); }
        float s = 0.f;
#pragma unroll
        for (int k = 0; k < 25; k++) { sv[k] = __expf(sv[k] - mx); s += sv[k]; }
        float inv = 1.f / s;
        int pgl = ((i0 + (spx >> 3)) << 6) + j0 + (spx & 7);
        float* wp = wkout + (sp * 25) * 16384 + (b << 12) + pgl;
#pragma unroll
        for (int k = 0; k < 25; k++) wp[k * 16384] = sv[k] * inv;  // coalesced
    }
}

// ---------------- K3: gather + pixel rearrange ----------------
// grid 4096 = (b*64+i)*16 + cc(16 ch). 256 thr = 64 j x (2 p-pairs x 2 c-halves).
// LDS 21.8 KB -> 7 blocks/CU (28 waves) vs R5's 3 (12 waves).
__global__ __launch_bounds__(256) void gather_kernel(
    const float* __restrict__ x, const float* __restrict__ ws,
    float* __restrict__ out) {
    __shared__ float xs[16 * 5 * 68];                // 21.76 KB
    int t = threadIdx.x;
    int blk = blockIdx.x;
    int cc = blk & 15;
    int bi = blk >> 4;
    int b = bi >> 6, i = bi & 63;
    int j = t & 63;
    int g = t >> 6;
    int ph = g >> 1, ch = g & 1;

    // coalesced wk loads: wk2[(p*25+k)*16384 + b*4096 + i*64 + j]
    float w0[25], w1[25];
    {
        const float* wp = ws + OFF_WK + (ph * 50) * 16384 + (b << 12) + (i << 6) + j;
#pragma unroll
        for (int k = 0; k < 25; k++) {
            w0[k] = wp[k * 16384];
            w1[k] = wp[(25 + k) * 16384];
        }
    }

    // div-free-ish staging: aligned 64-float row core + guarded zero pads.
    {
        int lane = t & 63, cd0 = t >> 6;             // (c,dy) pairs, 4 at a time
        for (int cd = cd0; cd < 80; cd += 4) {
            int c = cd / 5, dy = cd - c * 5;
            int gi = i - 2 + dy;
            float v = 0.f;
            if ((unsigned)gi < 64u)
                v = x[((b * 256 + (cc << 4) + c) << 12) + (gi << 6) + lane];
            float* row = xs + cd * 68;
            row[2 + lane] = v;
            if (lane < 2) row[lane] = 0.f;           // gj < 0 pad
            if (lane >= 62) row[lane + 4] = 0.f;     // gj >= 64 pad
        }
    }
    __syncthreads();

    for (int c2 = ch; c2 < 16; c2 += 2) {
        const float* xb = xs + (c2 * 5) * 68 + j;    // u = j+dx -> gj = j+dx-2
        float a0 = 0.f, a1 = 0.f;
#pragma unroll
        for (int dy = 0; dy < 5; dy++) {
#pragma unroll
            for (int dx = 0; dx < 5; dx++) {
                float xv = xb[dy * 68 + dx];
                int k = dy * 5 + dx;
                a0 += xv * w0[k];
                a1 += xv * w1[k];
            }
        }
        int c = (cc << 4) + c2;
        float2 o2 = make_float2(a0, a1);
        *(float2*)(out + (((b * 256 + c) << 12) + (i << 6) + j) * 4 + ph * 2) = o2;
    }
}

// ---------------- fallback: round-3 fused kernel (correct, slow) ----------------
__global__ __launch_bounds__(512) void carafe_fused(
    const float* __restrict__ x, const float* __restrict__ Wc,
    const float* __restrict__ bc, const float* __restrict__ We,
    const float* __restrict__ be, float* __restrict__ out) {
    __shared__ float xs[32 * 144];
    __shared__ float fw[6656];
    __shared__ float wst[3600];
    const int t = threadIdx.x;
    const int blk = blockIdx.x;
    const int b = blk >> 6, tile = blk & 63;
    const int i0 = (tile >> 3) << 3, j0 = (tile & 7) << 3;
    const int wid = t >> 6, pix = t & 63;
    const int li = pix >> 3, lj = pix & 7;
    float facc[13];
#pragma unroll
    for (int q = 0; q < 13; q++) facc[q] = 0.f;
    for (int cc = 0; cc < 8; cc++) {
        for (int idx = t; idx < 32 * 144; idx += 512) {
            int c = idx / 144, pos = idx - c * 144;
            int r = pos / 12, u = pos - r * 12;
            int gi = i0 + r - 2, gj = j0 + u - 2;
            float v = 0.f;
            if ((unsigned)gi < 64u && (unsigned)gj < 64u)
                v = x[(((b * 256 + cc * 32 + c) << 12) + (gi << 6) + gj)];
            xs[idx] = v;
        }
        __syncthreads();
#pragma unroll
        for (int q = 0; q < 13; q++) {
            int idx = q * 512 + t;
            if (idx < 6400) {
                int m = idx / 100, pos = idx - m * 100;
                int fi = pos / 10, fj = pos - fi * 10;
                int tp = (fi + 1) * 12 + fj + 1;
                const float* wr = Wc + m * 256 + cc * 32;
                float a = facc[q];
                for (int c = 0; c < 32; c++) a += xs[c * 144 + tp] * wr[c];
                facc[q] = a;
            }
        }
        __syncthreads();
    }
#pragma unroll
    for (int q = 0; q < 13; q++) {
        int idx = q * 512 + t;
        if (idx < 6400) {
            int m = idx / 100, pos = idx - m * 100;
            int fi = pos / 10, fj = pos - fi * 10;
            int gi = i0 + fi - 1, gj = j0 + fj - 1;
            float v = facc[q] + bc[m];
            v = v > 0.f ? v : 0.f;
            if ((unsigned)gi >= 64u || (unsigned)gj >= 64u) v = 0.f;
            fw[idx] = v;
        }
    }
    float acc[13];
#pragma unroll
    for (int q = 0; q < 13; q++) acc[q] = 0.f;
    for (int mb = 0; mb < 16; mb++) {
        for (int idx = t; idx < 3600; idx += 512) {
            int mm = idx / 900, rem = idx - mm * 900;
            int o = rem / 9, rs = rem - o * 9;
            wst[idx] = We[o * 576 + (mb * 4 + mm) * 9 + rs];
        }
        __syncthreads();
#pragma unroll
        for (int mm = 0; mm < 4; mm++) {
            const float* fb = fw + (mb * 4 + mm) * 100 + li * 10 + lj;
            float f9[9];
#pragma unroll
            for (int r = 0; r < 3; r++)
#pragma unroll
                for (int s = 0; s < 3; s++) f9[r * 3 + s] = fb[r * 10 + s];
#pragma unroll
            for (int q = 0; q < 13; q++) {
                int o = q * 8 + wid;
                if (o < 100) {
                    const float* wr = wst + mm * 900 + o * 9;
                    float a = acc[q];
#pragma unroll
                    for (int rs = 0; rs < 9; rs++) a += f9[rs] * wr[rs];
                    acc[q] = a;
                }
            }
        }
        __syncthreads();
    }
#pragma unroll
    for (int q = 0; q < 13; q++) {
        int o = q * 8 + wid;
        if (o < 100) fw[pix * 104 + o] = acc[q];
    }
    __syncthreads();
    float sv[25];
    float inv = 0.f;
    const int sp = t >> 6, spx = t & 63;
    const bool act = (t < 256);
    if (act) {
        float mx = -1e30f;
#pragma unroll
        for (int k = 0; k < 25; k++) {
            sv[k] = fw[spx * 104 + sp * 25 + k] + be[sp * 25 + k];
            mx = fmaxf(mx, sv[k]);
        }
        float s = 0.f;
#pragma unroll
        for (int k = 0; k < 25; k++) { sv[k] = __expf(sv[k] - mx); s += sv[k]; }
        inv = 1.f / s;
    }
    __syncthreads();
    if (act) {
#pragma unroll
        for (int k = 0; k < 25; k++) fw[spx * 104 + k * 4 + sp] = sv[k] * inv;
    }
    __syncthreads();
    float w[25][4];
    const float4* wp = (const float4*)(fw + pix * 104);
#pragma unroll
    for (int k = 0; k < 25; k++) {
        float4 ww = wp[k];
        w[k][0] = ww.x; w[k][1] = ww.y; w[k][2] = ww.z; w[k][3] = ww.w;
    }
    const int pgl = ((i0 + li) << 6) + (j0 + lj);
    for (int cc = 0; cc < 8; cc++) {
        for (int idx = t; idx < 32 * 144; idx += 512) {
            int c = idx / 144, pos = idx - c * 144;
            int r = pos / 12, u = pos - r * 12;
            int gi = i0 + r - 2, gj = j0 + u - 2;
            float v = 0.f;
            if ((unsigned)gi < 64u && (unsigned)gj < 64u)
                v = x[(((b * 256 + cc * 32 + c) << 12) + (gi << 6) + gj)];
            xs[idx] = v;
        }
        __syncthreads();
        for (int c8 = wid; c8 < 32; c8 += 8) {
            const float* xc = xs + c8 * 144 + li * 12 + lj;
            float a0 = 0.f, a1 = 0.f, a2 = 0.f, a3 = 0.f;
#pragma unroll
            for (int dy = 0; dy < 5; dy++) {
#pragma unroll
                for (int dx = 0; dx < 5; dx++) {
                    float xv = xc[dy * 12 + dx];
                    const int k = dy * 5 + dx;
                    a0 += xv * w[k][0];
                    a1 += xv * w[k][1];
                    a2 += xv * w[k][2];
                    a3 += xv * w[k][3];
                }
            }
            int c = cc * 32 + c8;
            float4 o4 = make_float4(a0, a1, a2, a3);
            *(float4*)(out + (((long long)(b * 256 + c)) << 14) + pgl * 4) = o4;
        }
        __syncthreads();
    }
}

extern "C" void kernel_launch(void* const* d_in, const int* in_sizes, int n_in,
                              void* d_out, int out_size, void* d_ws, size_t ws_size,
                              hipStream_t stream) {
    const float* x  = (const float*)d_in[0];
    const float* Wc = (const float*)d_in[1];
    const float* bc = (const float*)d_in[2];
    const float* We = (const float*)d_in[3];
    const float* be = (const float*)d_in[4];
    float* out = (float*)d_out;

    if (ws_size >= (size_t)WS_FLOATS * sizeof(float)) {
        float* ws = (float*)d_ws;
        prep_kernel<<<252, 256, 0, stream>>>(Wc, We, ws);
        compress_kernel<<<1024, 256, 0, stream>>>(x, bc, ws, ws + OFF_FEAT);
        enc_kernel<<<256, 512, 0, stream>>>(be, ws, ws + OFF_WK);
        gather_kernel<<<4096, 256, 0, stream>>>(x, ws, out);
    } else {
        carafe_fused<<<256, 512, 0, stream>>>(x, Wc, bc, We, be, out);
    }
}